// Round 9
// baseline (105.133 us; speedup 1.0000x reference)
//
#include <hip/hip_runtime.h>
#include <math.h>

#define H 1024
#define W 1024
#define OH 1016
#define OW 1016
#define BH 8           // output rows per band (1016 = 8*127 exact, no tail)
#define NBANDS 127
#define NCHUNK 4       // 4 column chunks of 256 output cols
#define NIMG 8
#define NWG (NBANDS*NCHUNK*NIMG)   // 4064, divisible by 8 (bijective XCD swizzle)
#define EPS 1e-6f
#define INV25 (1.0f/25.0f)

// One WAVE (64 threads) per block; each wave owns a 256-col x 8-row output
// chunk and streams down it. No barriers / no sched fences.
// R9: dx/dy 5-row ring moved from LDS (10.5 KB) into REGISTERS (rox/roy[5][4],
// statically indexed in the fully unrolled loop). Halo-4 of the old row comes
// from __shfl_down(ring,1); only the seam lane uses LDS: a 160 B seam[5][2][4]
// it alone writes and reads (same-lane same-address -> ordered, fence-free).
// Rationale: R8 occupancy ~6 blocks/CU == 64KiB/10.75KiB -> LDS pool capped
// residency; the latency chain had no TLP to hide under.
// R5 lesson: launch_bounds(64,4) forced VGPR=64 -> scratch spill. Keep (64,2).
// R6 lesson: per-iteration sched_barrier(0) blocked software pipelining.
// R8 lesson: XCD swizzle cut FETCH 123->92 MB; keep it.

__device__ __forceinline__ float4 ld4(const float* p){ return *reinterpret_cast<const float4*>(p); }
__device__ __forceinline__ void st4(float* p, float4 v){ *reinterpret_cast<float4*>(p) = v; }

__device__ __forceinline__ void load12(const float* p, float v[12]) {
    float4 a = ld4(p), b = ld4(p + 4), c = ld4(p + 8);
    v[0]=a.x; v[1]=a.y; v[2]=a.z;  v[3]=a.w;
    v[4]=b.x; v[5]=b.y; v[6]=b.z;  v[7]=b.w;
    v[8]=c.x; v[9]=c.y; v[10]=c.z; v[11]=c.w;
}

__global__ __launch_bounds__(64, 2)
void yiq_gngc_wave(const float* __restrict__ x, const float* __restrict__ y,
                   float* __restrict__ out, long long Nper)
{
    __shared__ __align__(16) float seam[5][2][4];     // 160 B total LDS
    const int t  = (int)threadIdx.x;

    // ---- XCD-aware bijective swizzle (NWG % 8 == 0) ----
    const int wg  = (int)blockIdx.x;
    const int nid = (wg & 7) * (NWG / 8) + (wg >> 3);
    const int band  = nid % NBANDS;
    const int rest  = nid / NBANDS;        // 0..31
    const int chunk = rest & 3;
    const int b     = rest >> 2;           // image 0..7  (== XCD id)

    const int jc = chunk * 256;
    const int maxj = (jc + 252 < OW - 4) ? (jc + 252) : (OW - 4);  // 1012 on last chunk
    int j0 = jc + 4 * t; if (j0 > maxj) j0 = maxj;    // clamped lanes duplicate (benign)
    const bool lastlane = (j0 == maxj);               // owns the 4-col seam halo
    const int i0 = band * BH;
    const float* xb = x + (size_t)b * (H * W) + j0;
    const float* yb = y + (size_t)b * (H * W) + j0;

    float cs_x[12], cs_y[12];
    float cp1[8], cp2[8], cp3[8];
    float rox[5][4], roy[5][4];            // register ring: own 4 cols of last 5 dx/dy rows
    #pragma unroll
    for (int k = 0; k < 12; ++k) { cs_x[k] = 0.f; cs_y[k] = 0.f; }
    #pragma unroll
    for (int k = 0; k < 8; ++k) { cp1[k] = 0.f; cp2[k] = 0.f; cp3[k] = 0.f; }
    #pragma unroll
    for (int k = 0; k < 4; ++k) { rox[4][k] = 0.f; roy[4][k] = 0.f; }   // "row -1"
    if (lastlane) {
        float4 z = make_float4(0.f, 0.f, 0.f, 0.f);
        st4(&seam[4][0][0], z); st4(&seam[4][1][0], z);
    }

    // ---- initial input column sums over rows i0..i0+4 (x then y) ----
    #pragma unroll
    for (int r = 0; r < 5; ++r) {
        float vx[12];
        load12(xb + (size_t)(i0 + r) * W, vx);
        #pragma unroll
        for (int k = 0; k < 12; ++k) cs_x[k] += vx[k];
    }
    #pragma unroll
    for (int r = 0; r < 5; ++r) {
        float vy[12];
        load12(yb + (size_t)(i0 + r) * W, vy);
        #pragma unroll
        for (int k = 0; k < 12; ++k) cs_y[k] += vy[k];
    }

    // ---- prime dx/dy rows i0..i0+3 into ring slots 0..3; accumulate cp ----
    #pragma unroll
    for (int pr = 0; pr < 4; ++pr) {
        float xc[12], yc[12];
        load12(xb + (size_t)(i0 + pr + 2) * W, xc);   // center row
        load12(yb + (size_t)(i0 + pr + 2) * W, yc);
        float dxn[8], dyn[8];
        #pragma unroll
        for (int k = 0; k < 8; ++k) {
            float sx = cs_x[k] + cs_x[k+1] + cs_x[k+2] + cs_x[k+3] + cs_x[k+4];
            float sy = cs_y[k] + cs_y[k+1] + cs_y[k+2] + cs_y[k+3] + cs_y[k+4];
            dxn[k] = xc[k + 2] - sx * INV25;
            dyn[k] = yc[k + 2] - sy * INV25;
            cp1[k] += dxn[k] * dyn[k];
            cp2[k] += dxn[k] * dxn[k];
            cp3[k] += dyn[k] * dyn[k];
        }
        #pragma unroll
        for (int k = 0; k < 4; ++k) { rox[pr][k] = dxn[k]; roy[pr][k] = dyn[k]; }
        if (lastlane) {
            st4(&seam[pr][0][0], make_float4(dxn[4], dxn[5], dxn[6], dxn[7]));
            st4(&seam[pr][1][0], make_float4(dyn[4], dyn[5], dyn[6], dyn[7]));
        }
        // slide cs: add row i0+pr+5, drop row i0+pr (x-pair then y-pair)
        {
            float nx[12], ox[12];
            load12(xb + (size_t)(i0 + pr + 5) * W, nx);
            load12(xb + (size_t)(i0 + pr) * W, ox);
            #pragma unroll
            for (int k = 0; k < 12; ++k) cs_x[k] += nx[k] - ox[k];
        }
        {
            float ny[12], oy[12];
            load12(yb + (size_t)(i0 + pr + 5) * W, ny);
            load12(yb + (size_t)(i0 + pr) * W, oy);
            #pragma unroll
            for (int k = 0; k < 12; ++k) cs_y[k] += ny[k] - oy[k];
        }
    }

    float* ob = out + (size_t)b * ((size_t)OH * OW) + j0;

    // ---- main loop: output rows i0..i0+7 (fully unrolled, static ring slots) ----
    #pragma unroll
    for (int it = 0; it < BH; ++it) {
        const int i = i0 + it;
        const int s = (it + 4) % 5;                  // slot of dropped row i-1 == new row i+4

        // center row for new dx/dy row i+4  (max row 1021)
        float xc[12], yc[12];
        load12(xb + (size_t)(i + 6) * W, xc);
        load12(yb + (size_t)(i + 6) * W, yc);

        // --- old dx/dy (row i-1): own 4 from register ring, halo 4 via shfl
        //     from lane t+1's ring; seam lane reads its private LDS slot ---
        float o0 = rox[s][0], o1 = rox[s][1], o2 = rox[s][2], o3 = rox[s][3];
        float p0 = roy[s][0], p1 = roy[s][1], p2 = roy[s][2], p3 = roy[s][3];
        float hx0 = __shfl_down(o0, 1), hx1 = __shfl_down(o1, 1);
        float hx2 = __shfl_down(o2, 1), hx3 = __shfl_down(o3, 1);
        float hy0 = __shfl_down(p0, 1), hy1 = __shfl_down(p1, 1);
        float hy2 = __shfl_down(p2, 1), hy3 = __shfl_down(p3, 1);
        if (lastlane) {   // seam: cols beyond the chunk, kept in 160B LDS
            float4 dhx = ld4(&seam[s][0][0]);
            float4 dhy = ld4(&seam[s][1][0]);
            hx0 = dhx.x; hx1 = dhx.y; hx2 = dhx.z; hx3 = dhx.w;
            hy0 = dhy.x; hy1 = dhy.y; hy2 = dhy.z; hy3 = dhy.w;
        }

        // new dx/dy row i+4 (8 halo cols, in registers)
        float dxn[8], dyn[8];
        #pragma unroll
        for (int k = 0; k < 8; ++k) {
            float sx = cs_x[k] + cs_x[k+1] + cs_x[k+2] + cs_x[k+3] + cs_x[k+4];
            float sy = cs_y[k] + cs_y[k+1] + cs_y[k+2] + cs_y[k+3] + cs_y[k+4];
            dxn[k] = xc[k + 2] - sx * INV25;
            dyn[k] = yc[k + 2] - sy * INV25;
        }
        #pragma unroll
        for (int k = 0; k < 4; ++k) { rox[s][k] = dxn[k]; roy[s][k] = dyn[k]; }
        if (lastlane) {
            st4(&seam[s][0][0], make_float4(dxn[4], dxn[5], dxn[6], dxn[7]));
            st4(&seam[s][1][0], make_float4(dyn[4], dyn[5], dyn[6], dyn[7]));
        }

        // slide product column sums: + new row, - old row
        float odx[8] = {o0, o1, o2, o3, hx0, hx1, hx2, hx3};
        float ody[8] = {p0, p1, p2, p3, hy0, hy1, hy2, hy3};
        #pragma unroll
        for (int k = 0; k < 8; ++k) {
            cp1[k] += dxn[k] * dyn[k] - odx[k] * ody[k];
            cp2[k] += dxn[k] * dxn[k] - odx[k] * odx[k];
            cp3[k] += dyn[k] * dyn[k] - ody[k] * ody[k];
        }

        // finalize output row i, cols j0..j0+3
        float co[4], vv[4], cc[4];
        #pragma unroll
        for (int q = 0; q < 4; ++q) {
            float c_ = (cp1[q] + cp1[q+1] + cp1[q+2] + cp1[q+3] + cp1[q+4]) * INV25;
            float vx = (cp2[q] + cp2[q+1] + cp2[q+2] + cp2[q+3] + cp2[q+4]) * INV25;
            float vy = (cp3[q] + cp3[q+1] + cp3[q+2] + cp3[q+3] + cp3[q+4]) * INV25;
            float v  = sqrtf(vx * vy);
            bool lo  = v < EPS;
            float cv = lo ? 0.f : c_;
            float vs = lo ? EPS : v;
            float r_ = cv / vs;
            r_ = r_ < 0.f ? 0.f : (r_ > 1.f ? 1.f : r_);
            co[q] = r_; vv[q] = vs; cc[q] = cv;
        }
        float* o = ob + (size_t)i * OW;
        st4(o,            make_float4(co[0], co[1], co[2], co[3]));
        st4(o + Nper,     make_float4(vv[0], vv[1], vv[2], vv[3]));
        st4(o + 2 * Nper, make_float4(cc[0], cc[1], cc[2], cc[3]));

        // slide input column sums: add row i+9 (max 1023), drop row i+4
        if (it < BH - 1) {
            {
                float nx[12], oxr[12];
                load12(xb + (size_t)(i + 9) * W, nx);
                load12(xb + (size_t)(i + 4) * W, oxr);
                #pragma unroll
                for (int k = 0; k < 12; ++k) cs_x[k] += nx[k] - oxr[k];
            }
            {
                float ny[12], oyr[12];
                load12(yb + (size_t)(i + 9) * W, ny);
                load12(yb + (size_t)(i + 4) * W, oyr);
                #pragma unroll
                for (int k = 0; k < 12; ++k) cs_y[k] += ny[k] - oyr[k];
            }
        }
    }
}

extern "C" void kernel_launch(void* const* d_in, const int* in_sizes, int n_in,
                              void* d_out, int out_size, void* d_ws, size_t ws_size,
                              hipStream_t stream) {
    const float* x = (const float*)d_in[0];
    const float* y = (const float*)d_in[1];
    // mask (d_in[2]) unused by the reference's channels==1 path
    float* out = (float*)d_out;
    const long long Nper = (long long)out_size / 3;   // elements per output array
    yiq_gngc_wave<<<dim3(NWG), dim3(64), 0, stream>>>(x, y, out, Nper);
}

// Round 11
// 64.597 us; speedup vs baseline: 1.6275x; 1.6275x over previous
//
#include <hip/hip_runtime.h>
#include <math.h>

#define H 1024
#define W 1024
#define OH 1016
#define OW 1016
#define BH 8           // output rows per band (1016 = 8*127 exact, no tail)
#define NBANDS 127
#define NCHUNK 4       // 4 column chunks of 256 output cols
#define NIMG 8
#define NWG (NBANDS*NCHUNK*NIMG)   // 4064, divisible by 8 (bijective XCD swizzle)
#define EPS 1e-6f
#define INV25 (1.0f/25.0f)

// One WAVE per block, streaming down a 256-col x 8-row chunk.
// R11 = R10 (raw-row LDS ring: each input row fetched from global ONCE) +
// explicit DS fences. R10 failed correctness; its logic is verified identical
// to passing R8 except LDS-RAW (write -> later read) dependencies on the raw
// ring, which have no hardware/compiler ordering guarantee without a wait.
// Fix: `s_waitcnt lgkmcnt(0)` ("memory" clobber) at the TOP of each prime/main
// iteration, AFTER issuing that iteration's global loads -- DS ops are
// ordered, vmcnt (global MLP) is untouched.
// R5 lesson: launch_bounds(64,4) forced VGPR=64 -> spill. Keep (64,2).
// R6 lesson: full sched fences block global-load pipelining. lgkm-only here.
// R8 lesson: XCD swizzle cut FETCH 123->92 MB; keep it.

#define LDS_FENCE() asm volatile("s_waitcnt lgkmcnt(0)" ::: "memory")

__device__ __forceinline__ float4 ld4(const float* p){ return *reinterpret_cast<const float4*>(p); }
__device__ __forceinline__ void st4(float* p, float4 v){ *reinterpret_cast<float4*>(p) = v; }

__device__ __forceinline__ void load12(const float* p, float v[12]) {
    float4 a = ld4(p), b = ld4(p + 4), c = ld4(p + 8);
    v[0]=a.x; v[1]=a.y; v[2]=a.z;  v[3]=a.w;
    v[4]=b.x; v[5]=b.y; v[6]=b.z;  v[7]=b.w;
    v[8]=c.x; v[9]=c.y; v[10]=c.z; v[11]=c.w;
}
__device__ __forceinline__ void st12s(float* p, const float v[12]) {
    st4(p,     make_float4(v[0], v[1], v[2],  v[3]));
    st4(p + 4, make_float4(v[4], v[5], v[6],  v[7]));
    st4(p + 8, make_float4(v[8], v[9], v[10], v[11]));
}

__global__ __launch_bounds__(64, 2)
void yiq_gngc_wave(const float* __restrict__ x, const float* __restrict__ y,
                   float* __restrict__ out, long long Nper)
{
    __shared__ __align__(16) float raw[6][2][264];    // 12672 B raw input row ring
    __shared__ __align__(16) float dring[5][2][264];  // 10560 B dx/dy ring
    const int t  = (int)threadIdx.x;

    // ---- XCD-aware bijective swizzle (NWG % 8 == 0) ----
    const int wg  = (int)blockIdx.x;
    const int nid = (wg & 7) * (NWG / 8) + (wg >> 3);
    const int band  = nid % NBANDS;
    const int rest  = nid / NBANDS;        // 0..31
    const int chunk = rest & 3;
    const int b     = rest >> 2;           // image 0..7

    const int jc = chunk * 256;
    const int maxj = (jc + 252 < OW - 4) ? (jc + 252) : (OW - 4);  // 1012 on last chunk
    int j0 = jc + 4 * t; if (j0 > maxj) j0 = maxj;    // clamped lanes duplicate (benign)
    const bool lastlane = (j0 == maxj);               // owns the 4-col dx-ring seam
    const int rel = j0 - jc;                          // 0..252; spans rel..rel+11 <= 263
    const int i0 = band * BH;
    const int m0 = i0 % 6;                            // raw-ring phase (wave-uniform)
    const float* xb = x + (size_t)b * (H * W) + j0;
    const float* yb = y + (size_t)b * (H * W) + j0;

    float cs_x[12], cs_y[12];
    float cp1[8], cp2[8], cp3[8];
    #pragma unroll
    for (int k = 0; k < 12; ++k) { cs_x[k] = 0.f; cs_y[k] = 0.f; }
    #pragma unroll
    for (int k = 0; k < 8; ++k) { cp1[k] = 0.f; cp2[k] = 0.f; cp3[k] = 0.f; }

    // ---- zero dx-ring slot 4 (the "row -1" subtracted at it=0) ----
    {
        float4 z = make_float4(0.f, 0.f, 0.f, 0.f);
        st4(&dring[4][0][rel], z); st4(&dring[4][1][rel], z);
        if (lastlane) { st4(&dring[4][0][rel + 4], z); st4(&dring[4][1][rel + 4], z); }
    }

    // ---- initial: rows i0..i0+4 from global -> cs sums + raw ring slots m0..m0+4 ----
    #pragma unroll
    for (int r = 0; r < 5; ++r) {
        int sl = m0 + r; if (sl >= 6) sl -= 6;
        float vx[12];
        load12(xb + (size_t)(i0 + r) * W, vx);
        st12s(&raw[sl][0][rel], vx);
        #pragma unroll
        for (int k = 0; k < 12; ++k) cs_x[k] += vx[k];
        float vy[12];
        load12(yb + (size_t)(i0 + r) * W, vy);
        st12s(&raw[sl][1][rel], vy);
        #pragma unroll
        for (int k = 0; k < 12; ++k) cs_y[k] += vy[k];
    }

    // ---- prime dx/dy rows i0..i0+3 into dring slots 0..3 ----
    #pragma unroll
    for (int pr = 0; pr < 4; ++pr) {
        // issue this iteration's global loads BEFORE the fence (vmcnt untouched)
        float nx[12], ny[12];
        load12(xb + (size_t)(i0 + pr + 5) * W, nx);
        load12(yb + (size_t)(i0 + pr + 5) * W, ny);
        LDS_FENCE();                                   // all prior DS writes committed
        int slc = m0 + pr + 2; if (slc >= 6) slc -= 6; // center row i0+pr+2
        float xc[12], yc[12];
        load12(&raw[slc][0][rel], xc);
        load12(&raw[slc][1][rel], yc);
        float dxn[8], dyn[8];
        #pragma unroll
        for (int k = 0; k < 8; ++k) {
            float sx = cs_x[k] + cs_x[k+1] + cs_x[k+2] + cs_x[k+3] + cs_x[k+4];
            float sy = cs_y[k] + cs_y[k+1] + cs_y[k+2] + cs_y[k+3] + cs_y[k+4];
            dxn[k] = xc[k + 2] - sx * INV25;
            dyn[k] = yc[k + 2] - sy * INV25;
            cp1[k] += dxn[k] * dyn[k];
            cp2[k] += dxn[k] * dxn[k];
            cp3[k] += dyn[k] * dyn[k];
        }
        st4(&dring[pr][0][rel], make_float4(dxn[0], dxn[1], dxn[2], dxn[3]));
        st4(&dring[pr][1][rel], make_float4(dyn[0], dyn[1], dyn[2], dyn[3]));
        if (lastlane) {
            st4(&dring[pr][0][rel + 4], make_float4(dxn[4], dxn[5], dxn[6], dxn[7]));
            st4(&dring[pr][1][rel + 4], make_float4(dyn[4], dyn[5], dyn[6], dyn[7]));
        }
        // slide cs: old from raw ring, new (global) into raw ring
        int sln = m0 + (pr + 5) % 6; if (sln >= 6) sln -= 6;
        int slo = m0 + pr;           if (slo >= 6) slo -= 6;
        {
            float ox[12], oy[12];
            load12(&raw[slo][0][rel], ox);
            load12(&raw[slo][1][rel], oy);
            st12s(&raw[sln][0][rel], nx);
            st12s(&raw[sln][1][rel], ny);
            #pragma unroll
            for (int k = 0; k < 12; ++k) { cs_x[k] += nx[k] - ox[k]; cs_y[k] += ny[k] - oy[k]; }
        }
    }

    float* ob = out + (size_t)b * ((size_t)OH * OW) + j0;

    // ---- main loop: output rows i0..i0+7 (fully unrolled) ----
    #pragma unroll
    for (int it = 0; it < BH; ++it) {
        const int i = i0 + it;
        const int s = (it + 4) % 5;                       // dx-ring slot (drop/new)
        int slc = m0 + (it % 6);       if (slc >= 6) slc -= 6;   // raw: center i+6
        int slo = m0 + ((it + 4) % 6); if (slo >= 6) slo -= 6;   // raw: old i+4
        int sln = m0 + ((it + 3) % 6); if (sln >= 6) sln -= 6;   // raw: new i+9

        // issue globals first (in flight across the DS fence)
        float nx[12], ny[12];
        if (it < BH - 1) {
            load12(xb + (size_t)(i + 9) * W, nx);          // max row 1023
            load12(yb + (size_t)(i + 9) * W, ny);
        }
        LDS_FENCE();                                       // prior DS writes committed

        // LDS reads: center row i+6 and (for slide) old row i+4
        float xc[12], yc[12];
        load12(&raw[slc][0][rel], xc);
        load12(&raw[slc][1][rel], yc);
        float ox[12], oy[12];
        if (it < BH - 1) {
            load12(&raw[slo][0][rel], ox);
            load12(&raw[slo][1][rel], oy);
        }

        // new dx/dy row i+4 (8 halo cols) from pre-slide cs
        float dxn[8], dyn[8];
        #pragma unroll
        for (int k = 0; k < 8; ++k) {
            float sx = cs_x[k] + cs_x[k+1] + cs_x[k+2] + cs_x[k+3] + cs_x[k+4];
            float sy = cs_y[k] + cs_y[k+1] + cs_y[k+2] + cs_y[k+3] + cs_y[k+4];
            dxn[k] = xc[k + 2] - sx * INV25;
            dyn[k] = yc[k + 2] - sy * INV25;
        }

        // --- old dx/dy (row i-1) from dx-ring: own 4 (read BEFORE overwrite)
        //     + halo 4 via shfl; seam lane reads its own rel+4 slot ---
        float4 oox = ld4(&dring[s][0][rel]);
        float4 ooy = ld4(&dring[s][1][rel]);
        float hx0 = __shfl_down(oox.x, 1), hx1 = __shfl_down(oox.y, 1);
        float hx2 = __shfl_down(oox.z, 1), hx3 = __shfl_down(oox.w, 1);
        float hy0 = __shfl_down(ooy.x, 1), hy1 = __shfl_down(ooy.y, 1);
        float hy2 = __shfl_down(ooy.z, 1), hy3 = __shfl_down(ooy.w, 1);
        if (lastlane) {
            float4 dhx = ld4(&dring[s][0][rel + 4]);
            float4 dhy = ld4(&dring[s][1][rel + 4]);
            hx0 = dhx.x; hx1 = dhx.y; hx2 = dhx.z; hx3 = dhx.w;
            hy0 = dhy.x; hy1 = dhy.y; hy2 = dhy.z; hy3 = dhy.w;
        }
        st4(&dring[s][0][rel], make_float4(dxn[0], dxn[1], dxn[2], dxn[3]));
        st4(&dring[s][1][rel], make_float4(dyn[0], dyn[1], dyn[2], dyn[3]));
        if (lastlane) {
            st4(&dring[s][0][rel + 4], make_float4(dxn[4], dxn[5], dxn[6], dxn[7]));
            st4(&dring[s][1][rel + 4], make_float4(dyn[4], dyn[5], dyn[6], dyn[7]));
        }

        // slide product column sums: + new row, - old row
        float odx[8] = {oox.x, oox.y, oox.z, oox.w, hx0, hx1, hx2, hx3};
        float ody[8] = {ooy.x, ooy.y, ooy.z, ooy.w, hy0, hy1, hy2, hy3};
        #pragma unroll
        for (int k = 0; k < 8; ++k) {
            cp1[k] += dxn[k] * dyn[k] - odx[k] * ody[k];
            cp2[k] += dxn[k] * dxn[k] - odx[k] * odx[k];
            cp3[k] += dyn[k] * dyn[k] - ody[k] * ody[k];
        }

        // finalize output row i, cols j0..j0+3
        float co[4], vv[4], cc[4];
        #pragma unroll
        for (int q = 0; q < 4; ++q) {
            float c_ = (cp1[q] + cp1[q+1] + cp1[q+2] + cp1[q+3] + cp1[q+4]) * INV25;
            float vx = (cp2[q] + cp2[q+1] + cp2[q+2] + cp2[q+3] + cp2[q+4]) * INV25;
            float vy = (cp3[q] + cp3[q+1] + cp3[q+2] + cp3[q+3] + cp3[q+4]) * INV25;
            float v  = sqrtf(vx * vy);
            bool lo  = v < EPS;
            float cv = lo ? 0.f : c_;
            float vs = lo ? EPS : v;
            float r_ = cv / vs;
            r_ = r_ < 0.f ? 0.f : (r_ > 1.f ? 1.f : r_);
            co[q] = r_; vv[q] = vs; cc[q] = cv;
        }
        float* o = ob + (size_t)i * OW;
        st4(o,            make_float4(co[0], co[1], co[2], co[3]));
        st4(o + Nper,     make_float4(vv[0], vv[1], vv[2], vv[3]));
        st4(o + 2 * Nper, make_float4(cc[0], cc[1], cc[2], cc[3]));

        // raw-ring write of the new row + cs slide
        if (it < BH - 1) {
            st12s(&raw[sln][0][rel], nx);
            st12s(&raw[sln][1][rel], ny);
            #pragma unroll
            for (int k = 0; k < 12; ++k) { cs_x[k] += nx[k] - ox[k]; cs_y[k] += ny[k] - oy[k]; }
        }
    }
}

extern "C" void kernel_launch(void* const* d_in, const int* in_sizes, int n_in,
                              void* d_out, int out_size, void* d_ws, size_t ws_size,
                              hipStream_t stream) {
    const float* x = (const float*)d_in[0];
    const float* y = (const float*)d_in[1];
    // mask (d_in[2]) unused by the reference's channels==1 path
    float* out = (float*)d_out;
    const long long Nper = (long long)out_size / 3;   // elements per output array
    yiq_gngc_wave<<<dim3(NWG), dim3(64), 0, stream>>>(x, y, out, Nper);
}